// Round 1
// baseline (392.642 us; speedup 1.0000x reference)
//
#include <hip/hip_runtime.h>
#include <math.h>

#define BB 32
#define TT 100
#define VV 10000
#define DD 128
#define OUTN 1000
#define G3 384

// ---------------------------------------------------------------------------
// K1: sparse embedding sum  e[b,t,:] = sum_{v: x!=0} x[b,t,v] * emb[v,:]
// grid = B*T blocks, 256 threads
// ---------------------------------------------------------------------------
__global__ __launch_bounds__(256) void k_embed(
    const float* __restrict__ x, const float* __restrict__ emb,
    float* __restrict__ e, int* __restrict__ mask)
{
    const int bt  = blockIdx.x;
    const int tid = threadIdx.x;
    __shared__ int   s_cnt;
    __shared__ int   s_any;
    __shared__ int   s_idx[256];
    __shared__ float s_val[256];
    if (tid == 0) { s_cnt = 0; s_any = 0; }
    __syncthreads();

    const float4* x4 = (const float4*)(x + (size_t)bt * VV);
    for (int i = tid; i < VV / 4; i += 256) {
        float4 v = x4[i];
        if (v.x != 0.f) { int p = atomicAdd(&s_cnt, 1); if (p < 256) { s_idx[p] = 4*i+0; s_val[p] = v.x; } }
        if (v.y != 0.f) { int p = atomicAdd(&s_cnt, 1); if (p < 256) { s_idx[p] = 4*i+1; s_val[p] = v.y; } }
        if (v.z != 0.f) { int p = atomicAdd(&s_cnt, 1); if (p < 256) { s_idx[p] = 4*i+2; s_val[p] = v.z; } }
        if (v.w != 0.f) { int p = atomicAdd(&s_cnt, 1); if (p < 256) { s_idx[p] = 4*i+3; s_val[p] = v.w; } }
    }
    __syncthreads();
    int cnt = s_cnt; if (cnt > 256) cnt = 256;
    if (tid < DD) {
        float acc = 0.f;
        for (int i = 0; i < cnt; ++i)
            acc += s_val[i] * emb[(size_t)s_idx[i] * DD + tid];
        e[(size_t)bt * DD + tid] = acc;
        if (acc != 0.f) s_any = 1;
    }
    __syncthreads();
    if (tid == 0) mask[bt] = s_any;
}

// ---------------------------------------------------------------------------
// K2: input-side gates  x3[row, 0:384]=e@wih_f^T+bih_f ; x3[row,384:768]=e@wih_b^T+bih_b
// grid = 400 blocks (8 rows each), 256 threads; each thread 3 cols x 8 rows
// ---------------------------------------------------------------------------
__global__ __launch_bounds__(256) void k_gates(
    const float* __restrict__ e,
    const float* __restrict__ wih_f, const float* __restrict__ bih_f,
    const float* __restrict__ wih_b, const float* __restrict__ bih_b,
    float* __restrict__ x3)
{
    const int r0  = blockIdx.x * 8;
    const int tid = threadIdx.x;
    __shared__ __align__(16) float se[8][DD];
    for (int i = tid; i < 8 * DD; i += 256)
        se[i >> 7][i & 127] = e[(size_t)(r0 + (i >> 7)) * DD + (i & 127)];
    __syncthreads();

    for (int cc = 0; cc < 3; ++cc) {
        const int col = tid + cc * 256;                 // 0..767
        const float* wrow;
        float bias;
        if (col < G3) { wrow = wih_f + (size_t)col * DD;        bias = bih_f[col]; }
        else          { wrow = wih_b + (size_t)(col - G3) * DD; bias = bih_b[col - G3]; }
        float acc[8];
        #pragma unroll
        for (int r = 0; r < 8; ++r) acc[r] = 0.f;
        const float4* w4 = (const float4*)wrow;
        for (int k4 = 0; k4 < DD / 4; ++k4) {
            float4 w = w4[k4];
            #pragma unroll
            for (int r = 0; r < 8; ++r) {
                float4 ev = *(const float4*)&se[r][4 * k4];
                acc[r] += ev.x * w.x + ev.y * w.y + ev.z * w.z + ev.w * w.w;
            }
        }
        #pragma unroll
        for (int r = 0; r < 8; ++r)
            x3[(size_t)(r0 + r) * 768 + col] = acc[r] + bias;
    }
}

// ---------------------------------------------------------------------------
// K3: GRU, one block per (batch, dir). 384 threads, whh row per thread in VGPRs.
// ---------------------------------------------------------------------------
__global__ __launch_bounds__(384) void k_gru(
    const float* __restrict__ x3,
    const float* __restrict__ whh_f, const float* __restrict__ bhh_f,
    const float* __restrict__ whh_b, const float* __restrict__ bhh_b,
    float* __restrict__ h_all)
{
    const int dir = blockIdx.x & 1;
    const int b   = blockIdx.x >> 1;
    const int g   = threadIdx.x;           // 0..383
    const float* whh = dir ? whh_b : whh_f;
    const float* bhh = dir ? bhh_b : bhh_f;

    float w[DD];
    const float4* wr4 = (const float4*)(whh + (size_t)g * DD);
    #pragma unroll
    for (int k4 = 0; k4 < DD / 4; ++k4) {
        float4 wv = wr4[k4];
        w[4*k4+0] = wv.x; w[4*k4+1] = wv.y; w[4*k4+2] = wv.z; w[4*k4+3] = wv.w;
    }
    const float bh = bhh[g];

    __shared__ __align__(16) float h_lds[DD];
    __shared__ float gh_lds[G3];
    float h_reg = 0.f;
    if (g < DD) h_lds[g] = 0.f;
    __syncthreads();

    for (int t = 0; t < TT; ++t) {
        const int te = dir ? (TT - 1 - t) : t;
        const float* x3p = x3 + (size_t)(b * TT + te) * 768 + dir * G3;
        float xr = 0.f, xz = 0.f, xn = 0.f;
        if (g < DD) { xr = x3p[g]; xz = x3p[DD + g]; xn = x3p[2 * DD + g]; }

        float acc = bh;
        #pragma unroll
        for (int k = 0; k < DD; k += 4) {
            float4 hv = *(const float4*)&h_lds[k];
            acc += w[k] * hv.x + w[k+1] * hv.y + w[k+2] * hv.z + w[k+3] * hv.w;
        }
        gh_lds[g] = acc;
        __syncthreads();

        if (g < DD) {
            float hr = gh_lds[g], hz = gh_lds[DD + g], hn = gh_lds[2 * DD + g];
            float r  = 1.f / (1.f + __expf(-(xr + hr)));
            float z  = 1.f / (1.f + __expf(-(xz + hz)));
            float n  = tanhf(xn + r * hn);
            float hnew = (1.f - z) * n + z * h_reg;
            h_reg = hnew;
            h_lds[g] = hnew;
            h_all[(size_t)((dir * BB + b) * TT + te) * DD + g] = hnew;
        }
        __syncthreads();
    }
}

// ---------------------------------------------------------------------------
// K4a: per-batch attention + h_last + combine -> feat[b,128]
// ---------------------------------------------------------------------------
__global__ __launch_bounds__(256) void k_attn(
    const float* __restrict__ h_all, const int* __restrict__ mask,
    const float* __restrict__ attn_w, const float* __restrict__ attn_b,
    const float* __restrict__ comb_w, const float* __restrict__ comb_b,
    float* __restrict__ feat)
{
    const int b   = blockIdx.x;
    const int tid = threadIdx.x;
    __shared__ float s_aw[256];
    __shared__ float s_sc[128];
    __shared__ int   s_m[128];
    __shared__ float s_red[128];
    __shared__ __align__(16) float s_ch[512];

    s_aw[tid] = attn_w[tid];
    int m = 0;
    if (tid < 128) {
        m = (tid < TT) ? mask[b * TT + tid] : 0;
        s_m[tid] = m;
    }
    __syncthreads();
    for (int s = 64; s > 0; s >>= 1) {
        if (tid < s) s_m[tid] += s_m[tid + s];
        __syncthreads();
    }
    const int last = s_m[0] - 1;

    const float* hf = h_all + (size_t)(0 * BB + b) * TT * DD;
    const float* hb = h_all + (size_t)(1 * BB + b) * TT * DD;

    float sc = -1e9f;
    if (tid < TT) {
        float a = attn_b[0];
        const float4* hf4 = (const float4*)(hf + (size_t)tid * DD);
        const float4* hb4 = (const float4*)(hb + (size_t)tid * DD);
        for (int k = 0; k < DD / 4; ++k) {
            float4 v = hf4[k];
            a += v.x * s_aw[4*k] + v.y * s_aw[4*k+1] + v.z * s_aw[4*k+2] + v.w * s_aw[4*k+3];
        }
        for (int k = 0; k < DD / 4; ++k) {
            float4 v = hb4[k];
            a += v.x * s_aw[DD+4*k] + v.y * s_aw[DD+4*k+1] + v.z * s_aw[DD+4*k+2] + v.w * s_aw[DD+4*k+3];
        }
        sc = m ? a : -1e9f;
    }
    if (tid < 128) { s_sc[tid] = sc; s_red[tid] = sc; }
    __syncthreads();
    for (int s = 64; s > 0; s >>= 1) {
        if (tid < s) s_red[tid] = fmaxf(s_red[tid], s_red[tid + s]);
        __syncthreads();
    }
    const float mx = s_red[0];
    __syncthreads();
    float ex = 0.f;
    if (tid < 128) { ex = __expf(s_sc[tid] - mx); s_sc[tid] = ex; s_red[tid] = ex; }
    __syncthreads();
    for (int s = 64; s > 0; s >>= 1) {
        if (tid < s) s_red[tid] += s_red[tid + s];
        __syncthreads();
    }
    const float inv = 1.f / s_red[0];
    __syncthreads();

    {
        const int fl = tid & 127;
        const float* hp = (tid < 128) ? hf : hb;
        float csum = 0.f;
        for (int t = 0; t < TT; ++t)
            csum += s_sc[t] * hp[(size_t)t * DD + fl];
        s_ch[tid]       = csum * inv;
        s_ch[256 + tid] = hp[(size_t)last * DD + fl];
    }
    __syncthreads();

    if (tid < 128) {
        float a = comb_b[tid];
        const float4* cw = (const float4*)(comb_w + (size_t)tid * 512);
        for (int k = 0; k < 128; ++k) {
            float4 w4 = cw[k];
            float4 v4 = *(const float4*)&s_ch[4 * k];
            a += w4.x * v4.x + w4.y * v4.y + w4.z * v4.z + w4.w * v4.w;
        }
        feat[(size_t)b * DD + tid] = tanhf(a);
    }
}

// ---------------------------------------------------------------------------
// K4b: logits = feat @ fc_w^T + fc_b   grid = B*4 blocks, 256 threads
// ---------------------------------------------------------------------------
__global__ __launch_bounds__(256) void k_logits(
    const float* __restrict__ feat, const float* __restrict__ fc_w,
    const float* __restrict__ fc_b, float* __restrict__ out)
{
    const int b   = blockIdx.x >> 2;
    const int oc  = blockIdx.x & 3;
    const int tid = threadIdx.x;
    const int o   = oc * 256 + tid;
    __shared__ __align__(16) float s_f[DD];
    if (tid < DD) s_f[tid] = feat[(size_t)b * DD + tid];
    __syncthreads();
    if (o < OUTN) {
        float a = fc_b[o];
        const float4* w4 = (const float4*)(fc_w + (size_t)o * DD);
        for (int k = 0; k < DD / 4; ++k) {
            float4 w = w4[k];
            float4 v = *(const float4*)&s_f[4 * k];
            a += w.x * v.x + w.y * v.y + w.z * v.z + w.w * v.w;
        }
        out[(size_t)b * OUTN + o] = a;
    }
}

// ---------------------------------------------------------------------------
extern "C" void kernel_launch(void* const* d_in, const int* in_sizes, int n_in,
                              void* d_out, int out_size, void* d_ws, size_t ws_size,
                              hipStream_t stream)
{
    const float* x      = (const float*)d_in[0];
    const float* emb    = (const float*)d_in[1];
    const float* wih_f  = (const float*)d_in[2];
    const float* whh_f  = (const float*)d_in[3];
    const float* bih_f  = (const float*)d_in[4];
    const float* bhh_f  = (const float*)d_in[5];
    const float* wih_b  = (const float*)d_in[6];
    const float* whh_b  = (const float*)d_in[7];
    const float* bih_b  = (const float*)d_in[8];
    const float* bhh_b  = (const float*)d_in[9];
    const float* attn_w = (const float*)d_in[10];
    const float* attn_b = (const float*)d_in[11];
    const float* comb_w = (const float*)d_in[12];
    const float* comb_b = (const float*)d_in[13];
    const float* fc_w   = (const float*)d_in[14];
    const float* fc_b   = (const float*)d_in[15];
    float* out = (float*)d_out;

    // workspace layout (floats)
    float* ws    = (float*)d_ws;
    float* e     = ws;                    // 409600
    int*   mask  = (int*)(ws + 409600);   // 3200
    float* x3    = ws + 412800;           // 2457600
    float* h_all = ws + 2870400;          // 819200
    float* feat  = ws + 3689600;          // 4096   (total ~14.1 MB)

    k_embed <<<BB * TT,      256, 0, stream>>>(x, emb, e, mask);
    k_gates <<<(BB * TT)/8,  256, 0, stream>>>(e, wih_f, bih_f, wih_b, bih_b, x3);
    k_gru   <<<2 * BB,       384, 0, stream>>>(x3, whh_f, bhh_f, whh_b, bhh_b, h_all);
    k_attn  <<<BB,           256, 0, stream>>>(h_all, mask, attn_w, attn_b, comb_w, comb_b, feat);
    k_logits<<<BB * 4,       256, 0, stream>>>(feat, fc_w, fc_b, out);
}